// Round 17
// baseline (324.668 us; speedup 1.0000x reference)
//
#include <hip/hip_runtime.h>
#include <hip/hip_bf16.h>
#include <math.h>

#define VV 50000
#define EE 300
#define HD 256
#define BB 256
#define TT 64
#define NEGV -1e9f

// ws layout (floats), full path:
//   OFF_HF : tagged u32 hfrag [2 buf][2 dir][16 bg][8192 u32]  (4 MB)
//            word = (h_bf16 << 16) | step_tag  -> data IS the sync
#define OFF_HF   0          // 1048576 floats
#define OFF_B2   1048576    // [2 dir][1024] gate-interleaved bias  2048
#define OFF_WHHF 1050624    // bf16 frags [dir][ngrp64][kt8][lane64][hi8|lo8] = 524288 fl
#define OFF_WIHF 1574912    // bf16 frags [dir][ngrp64][kt10][lane64][8] = 327680 fl
#define WS_FULL_BYTES (1902592ULL * 4ULL)
// fallback layout:
#define FB_H 0
#define FB_C 262144

typedef __attribute__((ext_vector_type(8))) short bf16x8;
typedef __attribute__((ext_vector_type(4))) float f32x4;

__device__ __forceinline__ float sigf(float x) {
  return 1.f / (1.f + __expf(-x));
}
__device__ __forceinline__ float tanhfast(float x) {
  return 1.f - 2.f / (__expf(2.f * x) + 1.f);
}
__device__ __forceinline__ unsigned short f2bf(float f) {
  union { float f; unsigned u; } x;
  x.f = f;
  unsigned r = x.u + 0x7fffu + ((x.u >> 16) & 1u);
  return (unsigned short)(r >> 16);
}

// ---------------- full-path prep ------------------------------------------
__global__ __launch_bounds__(256) void prep_all(
    const float* __restrict__ whf, const float* __restrict__ whb,
    const float* __restrict__ wif, const float* __restrict__ wib,
    const float* __restrict__ bf, const float* __restrict__ bb,
    float* __restrict__ ws) {
  int idx = blockIdx.x * 256 + threadIdx.x;
  if (idx < 131072) {
    unsigned* hb = (unsigned*)(ws + OFF_HF);
    hb[idx] = 0u;            // payload 0, tag 0
    hb[idx + 131072] = 0u;
  }
  if (idx < 2048) {
    int dir = idx >> 10, jg = idx & 1023, j = jg >> 2, g = jg & 3;
    ws[OFF_B2 + idx] = (dir ? bb : bf)[g * HD + j];
  }
  if (idx < 65536) {
    int lane = idx & 63, kt = (idx >> 6) & 7, ngrp = (idx >> 9) & 63,
        dir = idx >> 15;
    int n = ngrp * 16 + (lane & 15);
    int j = n >> 2, g = n & 3;
    int k0 = kt * 32 + (lane >> 4) * 8;
    const float* W = dir ? whb : whf;
    const float* src = W + (size_t)((g << 8) + j) * HD + k0;
    union { unsigned short u[8]; uint4 q; } hp, lp;
#pragma unroll
    for (int e = 0; e < 8; ++e) {
      float v = src[e];
      unsigned short hh = f2bf(v);
      union { unsigned u; float f; } hf;
      hf.u = (unsigned)hh << 16;
      hp.u[e] = hh;
      lp.u[e] = f2bf(v - hf.f);
    }
    unsigned short* dst = (unsigned short*)(ws + OFF_WHHF) + (size_t)idx * 16;
    *(uint4*)dst = hp.q;
    *(uint4*)(dst + 8) = lp.q;
  }
  if (idx < 81920) {
    int lane = idx & 63;
    int f = idx >> 6;
    int kt = f % 10;
    int ngrp = (f / 10) & 63;
    int dir = f / 640;
    int n = ngrp * 16 + (lane & 15);
    int j = n >> 2, g = n & 3;
    int k0 = kt * 32 + (lane >> 4) * 8;
    const float* W = dir ? wib : wif;
    union { unsigned short u[8]; uint4 q; } p;
#pragma unroll
    for (int e = 0; e < 8; ++e) {
      int k = k0 + e;
      p.u[e] = (k < EE) ? f2bf(W[(size_t)((g << 8) + j) * EE + k])
                        : (unsigned short)0;
    }
    *(uint4*)((unsigned short*)(ws + OFF_WIHF) + (size_t)idx * 8) = p.q;
  }
}

// ---------------- fallback init ---------------------------------------------
__global__ __launch_bounds__(256) void init_kernel(float* __restrict__ ws,
                                                   float* __restrict__ out) {
  int idx = blockIdx.x * 256 + threadIdx.x;
  if (idx < 393216) ws[idx] = 0.f;
  if (idx < BB * 2 * HD) out[idx] = NEGV;
}

// ---------------- persistent recurrence -------------------------------------
// grid = (16 bg, 8 slice, 2 dir) x 512 thr, 1 block/CU. Chain = 8 slice-blocks.
// Tag-in-word h exchange (r15, best measured): u32 = (bf16<<16)|step_tag via
// relaxed agent atomics; data IS the sync. r17 refinements:
//  - double-batch poll: one 8-load batch always in flight -> detection delay
//    ~1 round trip instead of ~1.5-2 (miss no longer costs a full re-issue).
//  - emb MFMAs hoisted ABOVE the poll (depend only on last step's ebuf,
//    ordered by sync2; prologue syncthreads covers s=0) -> compute overlaps
//    the wait and the post-poll critical path shortens.
__global__ __launch_bounds__(512) void lstm_persist(
    const int* __restrict__ tok, const int* __restrict__ lens,
    const float* __restrict__ emb, float* __restrict__ ws,
    float* __restrict__ out) {
  const int bg = blockIdx.x;     // 0..15 (16 batch rows)
  const int slice = blockIdx.y;  // 0..7  (128 jg = 32 j)
  const int dir = blockIdx.z;    // 0..1
  const int tid = threadIdx.x;
  const int lane = tid & 63;
  const int wv = tid >> 6;

  __shared__ __align__(16) unsigned short hfr[2][512][8];  // 16 KB chain h-frags
  __shared__ __align__(16) unsigned short ebuf[2][5120];   // emb A-frags, dbuf

  // resident W fragments
  bf16x8 whi[8], wlo[8], wih[10];
  const int ngrp = slice * 8 + wv;
  {
    const unsigned short* p = (const unsigned short*)(ws + OFF_WHHF) +
                              (size_t)(((dir * 64 + ngrp) * 8) * 64 + lane) * 16;
#pragma unroll
    for (int kt = 0; kt < 8; ++kt) {
      whi[kt] = *(const bf16x8*)(p + kt * 1024);
      wlo[kt] = *(const bf16x8*)(p + kt * 1024 + 8);
    }
    const unsigned short* q = (const unsigned short*)(ws + OFF_WIHF) +
                              (size_t)(((dir * 64 + ngrp) * 10) * 64 + lane) * 8;
#pragma unroll
    for (int kt = 0; kt < 10; ++kt) wih[kt] = *(const bf16x8*)(q + kt * 512);
  }

  // staging identity (emb path)
  const int rg = tid >> 5;  // row 0..15
  const int k8 = tid & 31;  // k-octet
  const int stage_row = bg * 16 + rg;
  const int strow = stage_row * TT;
  const int o2 = 32 + (k8 & 7);
  const bool has2 = (k8 < 8);
  const int swz_r = (rg >> 1) & 3;
  const int slot1 = (k8 >> 2) * 64 + rg * 4 + ((k8 & 3) ^ swz_r);
  const int slot2 = (o2 >> 2) * 64 + rg * 4 + ((o2 & 3) ^ swz_r);

  // gate identity (matches MFMA D layout after quad transpose)
  const int q = lane & 3;
  const int base = lane & 12;
  const int r = (lane >> 4) * 4 + q;             // 0..15
  const int gate_row = bg * 16 + r;
  const int len = lens[gate_row];
  const int jloc = ngrp * 4 + (base >> 2);       // global j 0..255
  const float4 bias4 =
      *(const float4*)(ws + OFF_B2 + dir * 1024 + ngrp * 16 + base);
  // producer word index: slot = kt(j)*64 + r*4 + (oct(j) ^ swz(r)), e = j&7
  const int wslot =
      (jloc >> 5) * 64 + r * 4 + (((jloc >> 3) & 3) ^ ((r >> 1) & 3));
  const int widx = wslot * 8 + (jloc & 7);

  // consumer frag index (swizzled)
  const int ld_r = lane & 15, ld_oct = lane >> 4;
  const int ld_slot = ld_r * 4 + (ld_oct ^ ((ld_r >> 1) & 3));

  unsigned* hfg = (unsigned*)(ws + OFF_HF);  // u32 units

  float c = 0.f, omax = NEGV, h_prev = 0.f;

  // ---- prologue: stage ebuf[0] for t(0) ----
  {
    const int t0 = dir ? (TT - 1) : 0;
    const float* er = emb + (size_t)tok[strow + t0] * EE;
    float4 a0 = *(const float4*)(er + k8 * 8);
    float4 a1 = *(const float4*)(er + k8 * 8 + 4);
    union { unsigned short u[8]; uint4 q; } p;
    p.u[0] = f2bf(a0.x); p.u[1] = f2bf(a0.y); p.u[2] = f2bf(a0.z);
    p.u[3] = f2bf(a0.w); p.u[4] = f2bf(a1.x); p.u[5] = f2bf(a1.y);
    p.u[6] = f2bf(a1.z); p.u[7] = f2bf(a1.w);
    *(uint4*)&ebuf[0][slot1 * 8] = p.q;
    if (has2) {
      float4 b0 = make_float4(0.f, 0.f, 0.f, 0.f);
      float4 b1 = make_float4(0.f, 0.f, 0.f, 0.f);
      if (o2 <= 37) b0 = *(const float4*)(er + o2 * 8);
      if (o2 < 37) b1 = *(const float4*)(er + o2 * 8 + 4);
      union { unsigned short u[8]; uint4 q; } p2;
      p2.u[0] = f2bf(b0.x); p2.u[1] = f2bf(b0.y); p2.u[2] = f2bf(b0.z);
      p2.u[3] = f2bf(b0.w); p2.u[4] = f2bf(b1.x); p2.u[5] = f2bf(b1.y);
      p2.u[6] = f2bf(b1.z); p2.u[7] = f2bf(b1.w);
      *(uint4*)&ebuf[0][slot2 * 8] = p2.q;
    }
  }
  __syncthreads();  // ebuf[0] visible (emb MFMAs now run before sync1)

  for (int s = 0; s < TT; ++s) {
    const int t = dir ? (TT - 1 - s) : s;
    const bool nstage = (s < TT - 1);
    // ---- 1. issue emb loads for t(s+1) ----
    float4 pe0, pe1, qe0, qe1;
    if (nstage) {
      const int tn = dir ? (TT - 2 - s) : (s + 1);
      const float* er = emb + (size_t)tok[strow + tn] * EE;
      pe0 = *(const float4*)(er + k8 * 8);
      pe1 = *(const float4*)(er + k8 * 8 + 4);
      qe0 = make_float4(0.f, 0.f, 0.f, 0.f);
      qe1 = make_float4(0.f, 0.f, 0.f, 0.f);
      if (has2) {
        if (o2 <= 37) qe0 = *(const float4*)(er + o2 * 8);
        if (o2 < 37) qe1 = *(const float4*)(er + o2 * 8 + 4);
      }
    }
    // ---- 2. emb MFMAs (last-step ebuf; ordered by sync2/prologue sync) ----
    f32x4 acc[4];
#pragma unroll
    for (int i = 0; i < 4; ++i) {
      acc[i][0] = 0.f; acc[i][1] = 0.f; acc[i][2] = 0.f; acc[i][3] = 0.f;
    }
    const unsigned short* eb = ebuf[s & 1];
#pragma unroll
    for (int kt = 0; kt < 10; ++kt) {
      bf16x8 ax = *(const bf16x8*)(eb + (kt * 64 + ld_slot) * 8);
      acc[kt & 3] =
          __builtin_amdgcn_mfma_f32_16x16x32_bf16(ax, wih[kt], acc[kt & 3], 0, 0, 0);
    }
    // ---- 3. double-batch tagged poll of this thread's 16 h words ----
    const unsigned long long* rsrc = (const unsigned long long*)(
        hfg + ((size_t)((s & 1) * 2 + dir) * 16 + bg) * 8192);
    const unsigned long long* r0 = rsrc + (size_t)tid * 4;
    const unsigned long long* r1 = rsrc + 2048 + (size_t)tid * 4;
    const unsigned long long expq =
        ((unsigned long long)((unsigned)s & 0xFFFFu)) |
        ((unsigned long long)((unsigned)s & 0xFFFFu) << 32);
    const unsigned long long TM = 0x0000FFFF0000FFFFull;
    unsigned long long w0, w1, w2, w3, w4, w5, w6, w7;
    {
      unsigned long long a0, a1, a2, a3, a4, a5, a6, a7;
      a0 = __hip_atomic_load(r0 + 0, __ATOMIC_RELAXED, __HIP_MEMORY_SCOPE_AGENT);
      a1 = __hip_atomic_load(r0 + 1, __ATOMIC_RELAXED, __HIP_MEMORY_SCOPE_AGENT);
      a2 = __hip_atomic_load(r0 + 2, __ATOMIC_RELAXED, __HIP_MEMORY_SCOPE_AGENT);
      a3 = __hip_atomic_load(r0 + 3, __ATOMIC_RELAXED, __HIP_MEMORY_SCOPE_AGENT);
      a4 = __hip_atomic_load(r1 + 0, __ATOMIC_RELAXED, __HIP_MEMORY_SCOPE_AGENT);
      a5 = __hip_atomic_load(r1 + 1, __ATOMIC_RELAXED, __HIP_MEMORY_SCOPE_AGENT);
      a6 = __hip_atomic_load(r1 + 2, __ATOMIC_RELAXED, __HIP_MEMORY_SCOPE_AGENT);
      a7 = __hip_atomic_load(r1 + 3, __ATOMIC_RELAXED, __HIP_MEMORY_SCOPE_AGENT);
      for (;;) {
        // issue batch B before inspecting batch A (keeps a batch in flight)
        unsigned long long b0, b1, b2, b3, b4, b5, b6, b7;
        b0 = __hip_atomic_load(r0 + 0, __ATOMIC_RELAXED, __HIP_MEMORY_SCOPE_AGENT);
        b1 = __hip_atomic_load(r0 + 1, __ATOMIC_RELAXED, __HIP_MEMORY_SCOPE_AGENT);
        b2 = __hip_atomic_load(r0 + 2, __ATOMIC_RELAXED, __HIP_MEMORY_SCOPE_AGENT);
        b3 = __hip_atomic_load(r0 + 3, __ATOMIC_RELAXED, __HIP_MEMORY_SCOPE_AGENT);
        b4 = __hip_atomic_load(r1 + 0, __ATOMIC_RELAXED, __HIP_MEMORY_SCOPE_AGENT);
        b5 = __hip_atomic_load(r1 + 1, __ATOMIC_RELAXED, __HIP_MEMORY_SCOPE_AGENT);
        b6 = __hip_atomic_load(r1 + 2, __ATOMIC_RELAXED, __HIP_MEMORY_SCOPE_AGENT);
        b7 = __hip_atomic_load(r1 + 3, __ATOMIC_RELAXED, __HIP_MEMORY_SCOPE_AGENT);
        unsigned long long dA = ((a0 ^ expq) | (a1 ^ expq) | (a2 ^ expq) |
                                 (a3 ^ expq) | (a4 ^ expq) | (a5 ^ expq) |
                                 (a6 ^ expq) | (a7 ^ expq)) & TM;
        if (dA == 0ull) {
          w0 = a0; w1 = a1; w2 = a2; w3 = a3;
          w4 = a4; w5 = a5; w6 = a6; w7 = a7;
          break;
        }
        a0 = __hip_atomic_load(r0 + 0, __ATOMIC_RELAXED, __HIP_MEMORY_SCOPE_AGENT);
        a1 = __hip_atomic_load(r0 + 1, __ATOMIC_RELAXED, __HIP_MEMORY_SCOPE_AGENT);
        a2 = __hip_atomic_load(r0 + 2, __ATOMIC_RELAXED, __HIP_MEMORY_SCOPE_AGENT);
        a3 = __hip_atomic_load(r0 + 3, __ATOMIC_RELAXED, __HIP_MEMORY_SCOPE_AGENT);
        a4 = __hip_atomic_load(r1 + 0, __ATOMIC_RELAXED, __HIP_MEMORY_SCOPE_AGENT);
        a5 = __hip_atomic_load(r1 + 1, __ATOMIC_RELAXED, __HIP_MEMORY_SCOPE_AGENT);
        a6 = __hip_atomic_load(r1 + 2, __ATOMIC_RELAXED, __HIP_MEMORY_SCOPE_AGENT);
        a7 = __hip_atomic_load(r1 + 3, __ATOMIC_RELAXED, __HIP_MEMORY_SCOPE_AGENT);
        unsigned long long dB = ((b0 ^ expq) | (b1 ^ expq) | (b2 ^ expq) |
                                 (b3 ^ expq) | (b4 ^ expq) | (b5 ^ expq) |
                                 (b6 ^ expq) | (b7 ^ expq)) & TM;
        if (dB == 0ull) {
          w0 = b0; w1 = b1; w2 = b2; w3 = b3;
          w4 = b4; w5 = b5; w6 = b6; w7 = b7;
          break;
        }
      }
    }
    // ---- 4. extract payload -> LDS (b128, lane-contiguous) + sync ----
    {
      const unsigned long long PM = 0xFFFF0000ull;
      uint4 p0, p1;
      p0.x = (unsigned)(((w0 >> 16) & 0xFFFFull) | ((w0 >> 32) & PM));
      p0.y = (unsigned)(((w1 >> 16) & 0xFFFFull) | ((w1 >> 32) & PM));
      p0.z = (unsigned)(((w2 >> 16) & 0xFFFFull) | ((w2 >> 32) & PM));
      p0.w = (unsigned)(((w3 >> 16) & 0xFFFFull) | ((w3 >> 32) & PM));
      p1.x = (unsigned)(((w4 >> 16) & 0xFFFFull) | ((w4 >> 32) & PM));
      p1.y = (unsigned)(((w5 >> 16) & 0xFFFFull) | ((w5 >> 32) & PM));
      p1.z = (unsigned)(((w6 >> 16) & 0xFFFFull) | ((w6 >> 32) & PM));
      p1.w = (unsigned)(((w7 >> 16) & 0xFFFFull) | ((w7 >> 32) & PM));
      *(uint4*)((char*)&hfr[0][0][0] + tid * 16) = p0;
      *(uint4*)((char*)&hfr[0][0][0] + 8192 + tid * 16) = p1;
    }
    __syncthreads();  // sync1: all h-frags present
    // ---- 5. h MFMAs (split hi/lo) ----
#pragma unroll
    for (int kt = 0; kt < 8; ++kt) {
      bf16x8 ahi = *(const bf16x8*)&hfr[0][kt * 64 + ld_slot][0];
      bf16x8 alo = *(const bf16x8*)&hfr[1][kt * 64 + ld_slot][0];
      f32x4 a = acc[kt & 3];
      a = __builtin_amdgcn_mfma_f32_16x16x32_bf16(ahi, whi[kt], a, 0, 0, 0);
      a = __builtin_amdgcn_mfma_f32_16x16x32_bf16(alo, whi[kt], a, 0, 0, 0);
      a = __builtin_amdgcn_mfma_f32_16x16x32_bf16(ahi, wlo[kt], a, 0, 0, 0);
      acc[kt & 3] = a;
    }
    f32x4 zf = (acc[0] + acc[1]) + (acc[2] + acc[3]);
    // ---- 6. quad 4x4 transpose: lane ends with all 4 gates of (r, jloc) ----
    float v0 = zf[0], v1 = zf[1], v2 = zf[2], v3 = zf[3];
    {
      float s0 = __shfl_xor(v1, 1), s1 = __shfl_xor(v0, 1);
      float s2 = __shfl_xor(v3, 1), s3 = __shfl_xor(v2, 1);
      const bool qb = (q & 1) != 0;
      float t0a = qb ? s0 : v0;
      float t1a = qb ? v1 : s1;
      float t2a = qb ? s2 : v2;
      float t3a = qb ? v3 : s3;
      float u0 = __shfl_xor(t2a, 2), u1 = __shfl_xor(t3a, 2);
      float u2 = __shfl_xor(t0a, 2), u3 = __shfl_xor(t1a, 2);
      const bool q2 = (q & 2) != 0;
      v0 = q2 ? u0 : t0a;
      v1 = q2 ? u1 : t1a;
      v2 = q2 ? t2a : u2;
      v3 = q2 ? t3a : u3;
    }
    // ---- 7. gates (lane-resident c / h_prev / omax) ----
    float h_out = h_prev;
    if (t < len) {
      float ig = sigf(v0 + bias4.x);
      float fg = sigf(v1 + bias4.y);
      float gg = tanhfast(v2 + bias4.z);
      float og = sigf(v3 + bias4.w);
      c = fg * c + ig * gg;
      float hn = og * tanhfast(c);
      h_out = hn;
      omax = fmaxf(omax, hn);
    }
    h_prev = h_out;
    if (nstage) {
      // ---- 8. producer: 2 tagged u32 stores (fire and forget) ----
      {
        unsigned short hi = f2bf(h_out);
        union { unsigned u; float f; } hf;
        hf.u = (unsigned)hi << 16;
        unsigned short lo = f2bf(h_out - hf.f);
        const unsigned tagn = (unsigned)(s + 1) & 0xFFFFu;
        unsigned* wdst =
            hfg + ((size_t)(((s + 1) & 1) * 2 + dir) * 16 + bg) * 8192;
        __hip_atomic_store(wdst + widx, ((unsigned)hi << 16) | tagn,
                           __ATOMIC_RELAXED, __HIP_MEMORY_SCOPE_AGENT);
        __hip_atomic_store(wdst + 4096 + widx, ((unsigned)lo << 16) | tagn,
                           __ATOMIC_RELAXED, __HIP_MEMORY_SCOPE_AGENT);
      }
      // ---- 9. convert prefetched emb -> ebuf[(s+1)&1] ----
      unsigned short* ebn = ebuf[(s + 1) & 1];
      {
        union { unsigned short u[8]; uint4 q; } p;
        p.u[0] = f2bf(pe0.x); p.u[1] = f2bf(pe0.y); p.u[2] = f2bf(pe0.z);
        p.u[3] = f2bf(pe0.w); p.u[4] = f2bf(pe1.x); p.u[5] = f2bf(pe1.y);
        p.u[6] = f2bf(pe1.z); p.u[7] = f2bf(pe1.w);
        *(uint4*)&ebn[slot1 * 8] = p.q;
        if (has2) {
          union { unsigned short u[8]; uint4 q; } p2;
          p2.u[0] = f2bf(qe0.x); p2.u[1] = f2bf(qe0.y); p2.u[2] = f2bf(qe0.z);
          p2.u[3] = f2bf(qe0.w); p2.u[4] = f2bf(qe1.x); p2.u[5] = f2bf(qe1.y);
          p2.u[6] = f2bf(qe1.z); p2.u[7] = f2bf(qe1.w);
          *(uint4*)&ebn[slot2 * 8] = p2.q;
        }
      }
      __syncthreads();  // sync2: ebuf ready; hfr reads done (safe to overwrite)
    }
  }
  out[(size_t)gate_row * (2 * HD) + dir * HD + jloc] = omax;
}

// ---------------- fallback (round-1 fused step) if ws too small ------------
__global__ __launch_bounds__(256) void step_fused(
    const int* __restrict__ tok, const int* __restrict__ lens,
    const float* __restrict__ emb,
    const float* __restrict__ wih_f, const float* __restrict__ whh_f,
    const float* __restrict__ bias_f,
    const float* __restrict__ wih_b, const float* __restrict__ whh_b,
    const float* __restrict__ bias_b,
    float* __restrict__ ws, float* __restrict__ out, int s) {
  const int tid = threadIdx.x;
  const int jt = blockIdx.x, bt = blockIdx.y, dir = blockIdx.z;
  const int j0 = jt * 32, b0g = bt * 16;
  const int t = (dir == 0) ? s : (TT - 1 - s);
  const float* Wih = dir ? wih_b : wih_f;
  const float* Whh = dir ? whh_b : whh_f;
  const float* bias = dir ? bias_b : bias_f;
  const float* hcur = ws + FB_H + (size_t)((s & 1) * 2 + dir) * BB * HD;
  float* hnxt = ws + FB_H + (size_t)(((s + 1) & 1) * 2 + dir) * BB * HD;
  float* cbuf = ws + FB_C + (size_t)dir * BB * HD;

  __shared__ float a_sm[16][64];
  __shared__ float w_sm[64][132];
  __shared__ float z_sm[16][132];

  const int cg = tid & 31, bgr = tid >> 5;
  float acc[2][4] = {{0.f, 0.f, 0.f, 0.f}, {0.f, 0.f, 0.f, 0.f}};

  for (int phase = 0; phase < 2; ++phase) {
    const float* W = phase ? Whh : Wih;
    const int K = phase ? HD : EE;
    for (int k0 = 0; k0 < K; k0 += 64) {
      const int klen = (K - k0) < 64 ? (K - k0) : 64;
      {
        int bl = tid >> 4, kk4 = tid & 15;
        if (kk4 * 4 < klen) {
          const float* src;
          if (phase == 0) {
            int tk = tok[(b0g + bl) * TT + t];
            src = emb + (size_t)tk * EE + k0 + kk4 * 4;
          } else {
            src = hcur + (size_t)(b0g + bl) * HD + k0 + kk4 * 4;
          }
          *(float4*)&a_sm[bl][kk4 * 4] = *(const float4*)src;
        }
      }
      for (int i = 0; i < 8; ++i) {
        int e = i * 256 + tid;
        int col = e >> 4, kk4 = e & 15;
        if (kk4 * 4 < klen) {
          int gcol = ((col >> 5) * HD) + j0 + (col & 31);
          float4 v = *(const float4*)(W + (size_t)gcol * K + k0 + kk4 * 4);
          w_sm[kk4 * 4 + 0][col] = v.x;
          w_sm[kk4 * 4 + 1][col] = v.y;
          w_sm[kk4 * 4 + 2][col] = v.z;
          w_sm[kk4 * 4 + 3][col] = v.w;
        }
      }
      __syncthreads();
      for (int k = 0; k < klen; ++k) {
        float a0 = a_sm[bgr * 2 + 0][k];
        float a1 = a_sm[bgr * 2 + 1][k];
        float4 w = *(const float4*)&w_sm[k][cg * 4];
        acc[0][0] += a0 * w.x; acc[0][1] += a0 * w.y;
        acc[0][2] += a0 * w.z; acc[0][3] += a0 * w.w;
        acc[1][0] += a1 * w.x; acc[1][1] += a1 * w.y;
        acc[1][2] += a1 * w.z; acc[1][3] += a1 * w.w;
      }
      __syncthreads();
    }
  }
  *(float4*)&z_sm[bgr * 2 + 0][cg * 4] =
      make_float4(acc[0][0], acc[0][1], acc[0][2], acc[0][3]);
  *(float4*)&z_sm[bgr * 2 + 1][cg * 4] =
      make_float4(acc[1][0], acc[1][1], acc[1][2], acc[1][3]);
  __syncthreads();
  for (int pi = 0; pi < 2; ++pi) {
    int p = pi * 256 + tid;
    int bl = p >> 5, jl = p & 31;
    int bglob = b0g + bl, jglob = j0 + jl;
    bool valid = t < lens[bglob];
    float h_old = hcur[(size_t)bglob * HD + jglob];
    float h_out = h_old;
    if (valid) {
      float zi = z_sm[bl][0 + jl] + bias[0 * HD + jglob];
      float zf = z_sm[bl][32 + jl] + bias[1 * HD + jglob];
      float zg = z_sm[bl][64 + jl] + bias[2 * HD + jglob];
      float zo = z_sm[bl][96 + jl] + bias[3 * HD + jglob];
      float ig = sigf(zi), fg = sigf(zf), gg = tanhf(zg), og = sigf(zo);
      float c_old = cbuf[(size_t)bglob * HD + jglob];
      float c_new = fg * c_old + ig * gg;
      float h_new = og * tanhf(c_new);
      cbuf[(size_t)bglob * HD + jglob] = c_new;
      h_out = h_new;
      float* op = out + (size_t)bglob * (2 * HD) + dir * HD + jglob;
      *op = fmaxf(*op, h_new);
    }
    hnxt[(size_t)bglob * HD + jglob] = h_out;
  }
}

extern "C" void kernel_launch(void* const* d_in, const int* in_sizes, int n_in,
                              void* d_out, int out_size, void* d_ws,
                              size_t ws_size, hipStream_t stream) {
  const int* tok = (const int*)d_in[0];
  const int* lens = (const int*)d_in[1];
  const float* emb = (const float*)d_in[2];
  const float* wih_f = (const float*)d_in[3];
  const float* whh_f = (const float*)d_in[4];
  const float* b_f = (const float*)d_in[5];
  const float* wih_b = (const float*)d_in[6];
  const float* whh_b = (const float*)d_in[7];
  const float* b_b = (const float*)d_in[8];
  float* out = (float*)d_out;
  float* ws = (float*)d_ws;

  const bool full = ws_size >= WS_FULL_BYTES;
  if (full) {
    hipLaunchKernelGGL(prep_all, dim3(512), dim3(256), 0, stream, whh_f,
                       whh_b, wih_f, wih_b, b_f, b_b, ws);
    hipLaunchKernelGGL(lstm_persist, dim3(16, 8, 2), dim3(512), 0, stream,
                       tok, lens, emb, ws, out);
  } else {
    hipLaunchKernelGGL(init_kernel, dim3(1536), dim3(256), 0, stream, ws, out);
    for (int s = 0; s < TT; ++s) {
      hipLaunchKernelGGL(step_fused, dim3(8, 16, 2), dim3(256), 0, stream, tok,
                         lens, emb, wih_f, whh_f, b_f, wih_b, whh_b, b_b, ws,
                         out, s);
    }
  }
}

// Round 18
// 206.727 us; speedup vs baseline: 1.5705x; 1.5705x over previous
//
#include <hip/hip_runtime.h>
#include <hip/hip_bf16.h>
#include <math.h>

#define VV 50000
#define EE 300
#define HD 256
#define BB 256
#define TT 64
#define NEGV -1e9f

// ws layout (floats), full path:
//   OFF_HF : tagged u32 hfrag [2 buf][2 dir][16 bg][8192 u32]  (4 MB)
//            word = (h_bf16 << 16) | step_tag  -> data IS the sync
#define OFF_HF   0          // 1048576 floats
#define OFF_B2   1048576    // [2 dir][1024] gate-interleaved bias  2048
#define OFF_WHHF 1050624    // bf16 frags [dir][ngrp64][kt8][lane64][hi8|lo8] = 524288 fl
#define OFF_WIHF 1574912    // bf16 frags [dir][ngrp64][kt10][lane64][8] = 327680 fl
#define WS_FULL_BYTES (1902592ULL * 4ULL)
// fallback layout:
#define FB_H 0
#define FB_C 262144

typedef __attribute__((ext_vector_type(8))) short bf16x8;
typedef __attribute__((ext_vector_type(4))) float f32x4;

__device__ __forceinline__ float sigf(float x) {
  return 1.f / (1.f + __expf(-x));
}
__device__ __forceinline__ float tanhfast(float x) {
  return 1.f - 2.f / (__expf(2.f * x) + 1.f);
}
__device__ __forceinline__ unsigned short f2bf(float f) {
  union { float f; unsigned u; } x;
  x.f = f;
  unsigned r = x.u + 0x7fffu + ((x.u >> 16) & 1u);
  return (unsigned short)(r >> 16);
}

// ---------------- full-path prep ------------------------------------------
//   idx < 131072 : zero tagged buf0 (2 u32 per thread -> 262144 words)
//   idx < 2048   : gate-interleaved bias
//   idx < 65536  : W_hh -> bf16 hi/lo MFMA B-fragments
//   idx < 81920  : W_ih -> bf16 MFMA B-fragments (K padded to 320)
__global__ __launch_bounds__(256) void prep_all(
    const float* __restrict__ whf, const float* __restrict__ whb,
    const float* __restrict__ wif, const float* __restrict__ wib,
    const float* __restrict__ bf, const float* __restrict__ bb,
    float* __restrict__ ws) {
  int idx = blockIdx.x * 256 + threadIdx.x;
  if (idx < 131072) {
    unsigned* hb = (unsigned*)(ws + OFF_HF);
    hb[idx] = 0u;            // payload 0, tag 0
    hb[idx + 131072] = 0u;
  }
  if (idx < 2048) {
    int dir = idx >> 10, jg = idx & 1023, j = jg >> 2, g = jg & 3;
    ws[OFF_B2 + idx] = (dir ? bb : bf)[g * HD + j];
  }
  if (idx < 65536) {
    int lane = idx & 63, kt = (idx >> 6) & 7, ngrp = (idx >> 9) & 63,
        dir = idx >> 15;
    int n = ngrp * 16 + (lane & 15);
    int j = n >> 2, g = n & 3;
    int k0 = kt * 32 + (lane >> 4) * 8;
    const float* W = dir ? whb : whf;
    const float* src = W + (size_t)((g << 8) + j) * HD + k0;
    union { unsigned short u[8]; uint4 q; } hp, lp;
#pragma unroll
    for (int e = 0; e < 8; ++e) {
      float v = src[e];
      unsigned short hh = f2bf(v);
      union { unsigned u; float f; } hf;
      hf.u = (unsigned)hh << 16;
      hp.u[e] = hh;
      lp.u[e] = f2bf(v - hf.f);
    }
    unsigned short* dst = (unsigned short*)(ws + OFF_WHHF) + (size_t)idx * 16;
    *(uint4*)dst = hp.q;
    *(uint4*)(dst + 8) = lp.q;
  }
  if (idx < 81920) {
    int lane = idx & 63;
    int f = idx >> 6;
    int kt = f % 10;
    int ngrp = (f / 10) & 63;
    int dir = f / 640;
    int n = ngrp * 16 + (lane & 15);
    int j = n >> 2, g = n & 3;
    int k0 = kt * 32 + (lane >> 4) * 8;
    const float* W = dir ? wib : wif;
    union { unsigned short u[8]; uint4 q; } p;
#pragma unroll
    for (int e = 0; e < 8; ++e) {
      int k = k0 + e;
      p.u[e] = (k < EE) ? f2bf(W[(size_t)((g << 8) + j) * EE + k])
                        : (unsigned short)0;
    }
    *(uint4*)((unsigned short*)(ws + OFF_WIHF) + (size_t)idx * 8) = p.q;
  }
}

// ---------------- fallback init ---------------------------------------------
__global__ __launch_bounds__(256) void init_kernel(float* __restrict__ ws,
                                                   float* __restrict__ out) {
  int idx = blockIdx.x * 256 + threadIdx.x;
  if (idx < 393216) ws[idx] = 0.f;
  if (idx < BB * 2 * HD) out[idx] = NEGV;
}

// ---------------- persistent recurrence -------------------------------------
// grid = (16 bg, 8 slice, 2 dir) x 512 thr, 1 block/CU. Chain = 8 slice-blocks.
// Tag-in-word h exchange: each h travels as u32 (bf16<<16)|step_tag via
// relaxed agent atomics. 4B-aligned stores are tear-free, so tag==step
// implies payload valid: NO vmcnt drain, NO flag line, NO writer phase.
// Buffer parity (2 bufs) + post-after-read makes overwrite impossible;
// equality tag check makes stale/poisoned data benign across graph replays.
__global__ __launch_bounds__(512) void lstm_persist(
    const int* __restrict__ tok, const int* __restrict__ lens,
    const float* __restrict__ emb, float* __restrict__ ws,
    float* __restrict__ out) {
  const int bg = blockIdx.x;     // 0..15 (16 batch rows)
  const int slice = blockIdx.y;  // 0..7  (128 jg = 32 j)
  const int dir = blockIdx.z;    // 0..1
  const int tid = threadIdx.x;
  const int lane = tid & 63;
  const int wv = tid >> 6;

  __shared__ __align__(16) unsigned short hfr[2][512][8];  // 16 KB chain h-frags
  __shared__ __align__(16) unsigned short ebuf[2][5120];   // emb A-frags, dbuf

  // resident W fragments
  bf16x8 whi[8], wlo[8], wih[10];
  const int ngrp = slice * 8 + wv;
  {
    const unsigned short* p = (const unsigned short*)(ws + OFF_WHHF) +
                              (size_t)(((dir * 64 + ngrp) * 8) * 64 + lane) * 16;
#pragma unroll
    for (int kt = 0; kt < 8; ++kt) {
      whi[kt] = *(const bf16x8*)(p + kt * 1024);
      wlo[kt] = *(const bf16x8*)(p + kt * 1024 + 8);
    }
    const unsigned short* q = (const unsigned short*)(ws + OFF_WIHF) +
                              (size_t)(((dir * 64 + ngrp) * 10) * 64 + lane) * 8;
#pragma unroll
    for (int kt = 0; kt < 10; ++kt) wih[kt] = *(const bf16x8*)(q + kt * 512);
  }

  // staging identity (emb path)
  const int rg = tid >> 5;  // row 0..15
  const int k8 = tid & 31;  // k-octet
  const int stage_row = bg * 16 + rg;
  const int strow = stage_row * TT;
  const int o2 = 32 + (k8 & 7);
  const bool has2 = (k8 < 8);
  const int swz_r = (rg >> 1) & 3;
  const int slot1 = (k8 >> 2) * 64 + rg * 4 + ((k8 & 3) ^ swz_r);
  const int slot2 = (o2 >> 2) * 64 + rg * 4 + ((o2 & 3) ^ swz_r);

  // gate identity (matches MFMA D layout after quad transpose)
  const int q = lane & 3;
  const int base = lane & 12;
  const int r = (lane >> 4) * 4 + q;             // 0..15
  const int gate_row = bg * 16 + r;
  const int len = lens[gate_row];
  const int jloc = ngrp * 4 + (base >> 2);       // global j 0..255
  const float4 bias4 =
      *(const float4*)(ws + OFF_B2 + dir * 1024 + ngrp * 16 + base);
  // producer word index: slot = kt(j)*64 + r*4 + (oct(j) ^ swz(r)), e = j&7
  const int wslot =
      (jloc >> 5) * 64 + r * 4 + (((jloc >> 3) & 3) ^ ((r >> 1) & 3));
  const int widx = wslot * 8 + (jloc & 7);

  // consumer frag index (swizzled)
  const int ld_r = lane & 15, ld_oct = lane >> 4;
  const int ld_slot = ld_r * 4 + (ld_oct ^ ((ld_r >> 1) & 3));

  unsigned* hfg = (unsigned*)(ws + OFF_HF);  // u32 units

  float c = 0.f, omax = NEGV, h_prev = 0.f;

  // ---- prologue: stage ebuf[0] for t(0) (loop's sync1 covers visibility) ----
  {
    const int t0 = dir ? (TT - 1) : 0;
    const float* er = emb + (size_t)tok[strow + t0] * EE;
    float4 a0 = *(const float4*)(er + k8 * 8);
    float4 a1 = *(const float4*)(er + k8 * 8 + 4);
    union { unsigned short u[8]; uint4 q; } p;
    p.u[0] = f2bf(a0.x); p.u[1] = f2bf(a0.y); p.u[2] = f2bf(a0.z);
    p.u[3] = f2bf(a0.w); p.u[4] = f2bf(a1.x); p.u[5] = f2bf(a1.y);
    p.u[6] = f2bf(a1.z); p.u[7] = f2bf(a1.w);
    *(uint4*)&ebuf[0][slot1 * 8] = p.q;
    if (has2) {
      float4 b0 = make_float4(0.f, 0.f, 0.f, 0.f);
      float4 b1 = make_float4(0.f, 0.f, 0.f, 0.f);
      if (o2 <= 37) b0 = *(const float4*)(er + o2 * 8);
      if (o2 < 37) b1 = *(const float4*)(er + o2 * 8 + 4);
      union { unsigned short u[8]; uint4 q; } p2;
      p2.u[0] = f2bf(b0.x); p2.u[1] = f2bf(b0.y); p2.u[2] = f2bf(b0.z);
      p2.u[3] = f2bf(b0.w); p2.u[4] = f2bf(b1.x); p2.u[5] = f2bf(b1.y);
      p2.u[6] = f2bf(b1.z); p2.u[7] = f2bf(b1.w);
      *(uint4*)&ebuf[0][slot2 * 8] = p2.q;
    }
  }

  for (int s = 0; s < TT; ++s) {
    const int t = dir ? (TT - 1 - s) : s;
    const bool nstage = (s < TT - 1);
    // ---- 1. issue emb loads for t(s+1) (overlap the poll) ----
    float4 pe0, pe1, qe0, qe1;
    if (nstage) {
      const int tn = dir ? (TT - 2 - s) : (s + 1);
      const float* er = emb + (size_t)tok[strow + tn] * EE;
      pe0 = *(const float4*)(er + k8 * 8);
      pe1 = *(const float4*)(er + k8 * 8 + 4);
      qe0 = make_float4(0.f, 0.f, 0.f, 0.f);
      qe1 = make_float4(0.f, 0.f, 0.f, 0.f);
      if (has2) {
        if (o2 <= 37) qe0 = *(const float4*)(er + o2 * 8);
        if (o2 < 37) qe1 = *(const float4*)(er + o2 * 8 + 4);
      }
    }
    // ---- 2. tagged poll-load of this thread's 16 h words ----
    const unsigned long long* rsrc = (const unsigned long long*)(
        hfg + ((size_t)((s & 1) * 2 + dir) * 16 + bg) * 8192);
    const unsigned long long* r0 = rsrc + (size_t)tid * 4;
    const unsigned long long* r1 = rsrc + 2048 + (size_t)tid * 4;
    const unsigned long long expq =
        ((unsigned long long)((unsigned)s & 0xFFFFu)) |
        ((unsigned long long)((unsigned)s & 0xFFFFu) << 32);
    unsigned long long w0, w1, w2, w3, w4, w5, w6, w7;
    for (;;) {
      w0 = __hip_atomic_load(r0 + 0, __ATOMIC_RELAXED, __HIP_MEMORY_SCOPE_AGENT);
      w1 = __hip_atomic_load(r0 + 1, __ATOMIC_RELAXED, __HIP_MEMORY_SCOPE_AGENT);
      w2 = __hip_atomic_load(r0 + 2, __ATOMIC_RELAXED, __HIP_MEMORY_SCOPE_AGENT);
      w3 = __hip_atomic_load(r0 + 3, __ATOMIC_RELAXED, __HIP_MEMORY_SCOPE_AGENT);
      w4 = __hip_atomic_load(r1 + 0, __ATOMIC_RELAXED, __HIP_MEMORY_SCOPE_AGENT);
      w5 = __hip_atomic_load(r1 + 1, __ATOMIC_RELAXED, __HIP_MEMORY_SCOPE_AGENT);
      w6 = __hip_atomic_load(r1 + 2, __ATOMIC_RELAXED, __HIP_MEMORY_SCOPE_AGENT);
      w7 = __hip_atomic_load(r1 + 3, __ATOMIC_RELAXED, __HIP_MEMORY_SCOPE_AGENT);
      const unsigned long long TM = 0x0000FFFF0000FFFFull;
      unsigned long long d = ((w0 ^ expq) | (w1 ^ expq) | (w2 ^ expq) |
                              (w3 ^ expq) | (w4 ^ expq) | (w5 ^ expq) |
                              (w6 ^ expq) | (w7 ^ expq)) & TM;
      if (d == 0ull) break;
    }
    // ---- 3. extract payload -> LDS (b128, lane-contiguous) + sync ----
    {
      const unsigned long long PM = 0xFFFF0000ull;
      uint4 p0, p1;
      p0.x = (unsigned)(((w0 >> 16) & 0xFFFFull) | ((w0 >> 32) & PM));
      p0.y = (unsigned)(((w1 >> 16) & 0xFFFFull) | ((w1 >> 32) & PM));
      p0.z = (unsigned)(((w2 >> 16) & 0xFFFFull) | ((w2 >> 32) & PM));
      p0.w = (unsigned)(((w3 >> 16) & 0xFFFFull) | ((w3 >> 32) & PM));
      p1.x = (unsigned)(((w4 >> 16) & 0xFFFFull) | ((w4 >> 32) & PM));
      p1.y = (unsigned)(((w5 >> 16) & 0xFFFFull) | ((w5 >> 32) & PM));
      p1.z = (unsigned)(((w6 >> 16) & 0xFFFFull) | ((w6 >> 32) & PM));
      p1.w = (unsigned)(((w7 >> 16) & 0xFFFFull) | ((w7 >> 32) & PM));
      *(uint4*)((char*)&hfr[0][0][0] + tid * 16) = p0;
      *(uint4*)((char*)&hfr[0][0][0] + 8192 + tid * 16) = p1;
    }
    __syncthreads();  // sync1: all h-frags + (iter0) ebuf present
    // ---- 4. MFMA: 10 emb + 24 h (split) ----
    f32x4 acc[4];
#pragma unroll
    for (int i = 0; i < 4; ++i) {
      acc[i][0] = 0.f; acc[i][1] = 0.f; acc[i][2] = 0.f; acc[i][3] = 0.f;
    }
    const unsigned short* eb = ebuf[s & 1];
#pragma unroll
    for (int kt = 0; kt < 10; ++kt) {
      bf16x8 ax = *(const bf16x8*)(eb + (kt * 64 + ld_slot) * 8);
      acc[kt & 3] =
          __builtin_amdgcn_mfma_f32_16x16x32_bf16(ax, wih[kt], acc[kt & 3], 0, 0, 0);
    }
#pragma unroll
    for (int kt = 0; kt < 8; ++kt) {
      bf16x8 ahi = *(const bf16x8*)&hfr[0][kt * 64 + ld_slot][0];
      bf16x8 alo = *(const bf16x8*)&hfr[1][kt * 64 + ld_slot][0];
      f32x4 a = acc[kt & 3];
      a = __builtin_amdgcn_mfma_f32_16x16x32_bf16(ahi, whi[kt], a, 0, 0, 0);
      a = __builtin_amdgcn_mfma_f32_16x16x32_bf16(alo, whi[kt], a, 0, 0, 0);
      a = __builtin_amdgcn_mfma_f32_16x16x32_bf16(ahi, wlo[kt], a, 0, 0, 0);
      acc[kt & 3] = a;
    }
    f32x4 zf = (acc[0] + acc[1]) + (acc[2] + acc[3]);
    // ---- 5. quad 4x4 transpose: lane ends with all 4 gates of (r, jloc) ----
    float v0 = zf[0], v1 = zf[1], v2 = zf[2], v3 = zf[3];
    {
      float s0 = __shfl_xor(v1, 1), s1 = __shfl_xor(v0, 1);
      float s2 = __shfl_xor(v3, 1), s3 = __shfl_xor(v2, 1);
      const bool qb = (q & 1) != 0;
      float t0a = qb ? s0 : v0;
      float t1a = qb ? v1 : s1;
      float t2a = qb ? s2 : v2;
      float t3a = qb ? v3 : s3;
      float u0 = __shfl_xor(t2a, 2), u1 = __shfl_xor(t3a, 2);
      float u2 = __shfl_xor(t0a, 2), u3 = __shfl_xor(t1a, 2);
      const bool q2 = (q & 2) != 0;
      v0 = q2 ? u0 : t0a;
      v1 = q2 ? u1 : t1a;
      v2 = q2 ? t2a : u2;
      v3 = q2 ? t3a : u3;
    }
    // ---- 6. gates (lane-resident c / h_prev / omax) ----
    float h_out = h_prev;
    if (t < len) {
      float ig = sigf(v0 + bias4.x);
      float fg = sigf(v1 + bias4.y);
      float gg = tanhfast(v2 + bias4.z);
      float og = sigf(v3 + bias4.w);
      c = fg * c + ig * gg;
      float hn = og * tanhfast(c);
      h_out = hn;
      omax = fmaxf(omax, hn);
    }
    h_prev = h_out;
    if (nstage) {
      // ---- 7. producer: 2 tagged u32 stores (fire and forget) ----
      {
        unsigned short hi = f2bf(h_out);
        union { unsigned u; float f; } hf;
        hf.u = (unsigned)hi << 16;
        unsigned short lo = f2bf(h_out - hf.f);
        const unsigned tagn = (unsigned)(s + 1) & 0xFFFFu;
        unsigned* wdst =
            hfg + ((size_t)(((s + 1) & 1) * 2 + dir) * 16 + bg) * 8192;
        __hip_atomic_store(wdst + widx, ((unsigned)hi << 16) | tagn,
                           __ATOMIC_RELAXED, __HIP_MEMORY_SCOPE_AGENT);
        __hip_atomic_store(wdst + 4096 + widx, ((unsigned)lo << 16) | tagn,
                           __ATOMIC_RELAXED, __HIP_MEMORY_SCOPE_AGENT);
      }
      // ---- 8. convert prefetched emb -> ebuf[(s+1)&1] ----
      unsigned short* ebn = ebuf[(s + 1) & 1];
      {
        union { unsigned short u[8]; uint4 q; } p;
        p.u[0] = f2bf(pe0.x); p.u[1] = f2bf(pe0.y); p.u[2] = f2bf(pe0.z);
        p.u[3] = f2bf(pe0.w); p.u[4] = f2bf(pe1.x); p.u[5] = f2bf(pe1.y);
        p.u[6] = f2bf(pe1.z); p.u[7] = f2bf(pe1.w);
        *(uint4*)&ebn[slot1 * 8] = p.q;
        if (has2) {
          union { unsigned short u[8]; uint4 q; } p2;
          p2.u[0] = f2bf(qe0.x); p2.u[1] = f2bf(qe0.y); p2.u[2] = f2bf(qe0.z);
          p2.u[3] = f2bf(qe0.w); p2.u[4] = f2bf(qe1.x); p2.u[5] = f2bf(qe1.y);
          p2.u[6] = f2bf(qe1.z); p2.u[7] = f2bf(qe1.w);
          *(uint4*)&ebn[slot2 * 8] = p2.q;
        }
      }
      __syncthreads();  // sync2: ebuf ready; hfr reads done (safe to overwrite)
    }
  }
  out[(size_t)gate_row * (2 * HD) + dir * HD + jloc] = omax;
}

// ---------------- fallback (round-1 fused step) if ws too small ------------
__global__ __launch_bounds__(256) void step_fused(
    const int* __restrict__ tok, const int* __restrict__ lens,
    const float* __restrict__ emb,
    const float* __restrict__ wih_f, const float* __restrict__ whh_f,
    const float* __restrict__ bias_f,
    const float* __restrict__ wih_b, const float* __restrict__ whh_b,
    const float* __restrict__ bias_b,
    float* __restrict__ ws, float* __restrict__ out, int s) {
  const int tid = threadIdx.x;
  const int jt = blockIdx.x, bt = blockIdx.y, dir = blockIdx.z;
  const int j0 = jt * 32, b0g = bt * 16;
  const int t = (dir == 0) ? s : (TT - 1 - s);
  const float* Wih = dir ? wih_b : wih_f;
  const float* Whh = dir ? whh_b : whh_f;
  const float* bias = dir ? bias_b : bias_f;
  const float* hcur = ws + FB_H + (size_t)((s & 1) * 2 + dir) * BB * HD;
  float* hnxt = ws + FB_H + (size_t)(((s + 1) & 1) * 2 + dir) * BB * HD;
  float* cbuf = ws + FB_C + (size_t)dir * BB * HD;

  __shared__ float a_sm[16][64];
  __shared__ float w_sm[64][132];
  __shared__ float z_sm[16][132];

  const int cg = tid & 31, bgr = tid >> 5;
  float acc[2][4] = {{0.f, 0.f, 0.f, 0.f}, {0.f, 0.f, 0.f, 0.f}};

  for (int phase = 0; phase < 2; ++phase) {
    const float* W = phase ? Whh : Wih;
    const int K = phase ? HD : EE;
    for (int k0 = 0; k0 < K; k0 += 64) {
      const int klen = (K - k0) < 64 ? (K - k0) : 64;
      {
        int bl = tid >> 4, kk4 = tid & 15;
        if (kk4 * 4 < klen) {
          const float* src;
          if (phase == 0) {
            int tk = tok[(b0g + bl) * TT + t];
            src = emb + (size_t)tk * EE + k0 + kk4 * 4;
          } else {
            src = hcur + (size_t)(b0g + bl) * HD + k0 + kk4 * 4;
          }
          *(float4*)&a_sm[bl][kk4 * 4] = *(const float4*)src;
        }
      }
      for (int i = 0; i < 8; ++i) {
        int e = i * 256 + tid;
        int col = e >> 4, kk4 = e & 15;
        if (kk4 * 4 < klen) {
          int gcol = ((col >> 5) * HD) + j0 + (col & 31);
          float4 v = *(const float4*)(W + (size_t)gcol * K + k0 + kk4 * 4);
          w_sm[kk4 * 4 + 0][col] = v.x;
          w_sm[kk4 * 4 + 1][col] = v.y;
          w_sm[kk4 * 4 + 2][col] = v.z;
          w_sm[kk4 * 4 + 3][col] = v.w;
        }
      }
      __syncthreads();
      for (int k = 0; k < klen; ++k) {
        float a0 = a_sm[bgr * 2 + 0][k];
        float a1 = a_sm[bgr * 2 + 1][k];
        float4 w = *(const float4*)&w_sm[k][cg * 4];
        acc[0][0] += a0 * w.x; acc[0][1] += a0 * w.y;
        acc[0][2] += a0 * w.z; acc[0][3] += a0 * w.w;
        acc[1][0] += a1 * w.x; acc[1][1] += a1 * w.y;
        acc[1][2] += a1 * w.z; acc[1][3] += a1 * w.w;
      }
      __syncthreads();
    }
  }
  *(float4*)&z_sm[bgr * 2 + 0][cg * 4] =
      make_float4(acc[0][0], acc[0][1], acc[0][2], acc[0][3]);
  *(float4*)&z_sm[bgr * 2 + 1][cg * 4] =
      make_float4(acc[1][0], acc[1][1], acc[1][2], acc[1][3]);
  __syncthreads();
  for (int pi = 0; pi < 2; ++pi) {
    int p = pi * 256 + tid;
    int bl = p >> 5, jl = p & 31;
    int bglob = b0g + bl, jglob = j0 + jl;
    bool valid = t < lens[bglob];
    float h_old = hcur[(size_t)bglob * HD + jglob];
    float h_out = h_old;
    if (valid) {
      float zi = z_sm[bl][0 + jl] + bias[0 * HD + jglob];
      float zf = z_sm[bl][32 + jl] + bias[1 * HD + jglob];
      float zg = z_sm[bl][64 + jl] + bias[2 * HD + jglob];
      float zo = z_sm[bl][96 + jl] + bias[3 * HD + jglob];
      float ig = sigf(zi), fg = sigf(zf), gg = tanhf(zg), og = sigf(zo);
      float c_old = cbuf[(size_t)bglob * HD + jglob];
      float c_new = fg * c_old + ig * gg;
      float h_new = og * tanhf(c_new);
      cbuf[(size_t)bglob * HD + jglob] = c_new;
      h_out = h_new;
      float* op = out + (size_t)bglob * (2 * HD) + dir * HD + jglob;
      *op = fmaxf(*op, h_new);
    }
    hnxt[(size_t)bglob * HD + jglob] = h_out;
  }
}

extern "C" void kernel_launch(void* const* d_in, const int* in_sizes, int n_in,
                              void* d_out, int out_size, void* d_ws,
                              size_t ws_size, hipStream_t stream) {
  const int* tok = (const int*)d_in[0];
  const int* lens = (const int*)d_in[1];
  const float* emb = (const float*)d_in[2];
  const float* wih_f = (const float*)d_in[3];
  const float* whh_f = (const float*)d_in[4];
  const float* b_f = (const float*)d_in[5];
  const float* wih_b = (const float*)d_in[6];
  const float* whh_b = (const float*)d_in[7];
  const float* b_b = (const float*)d_in[8];
  float* out = (float*)d_out;
  float* ws = (float*)d_ws;

  const bool full = ws_size >= WS_FULL_BYTES;
  if (full) {
    hipLaunchKernelGGL(prep_all, dim3(512), dim3(256), 0, stream, whh_f,
                       whh_b, wih_f, wih_b, b_f, b_b, ws);
    hipLaunchKernelGGL(lstm_persist, dim3(16, 8, 2), dim3(512), 0, stream,
                       tok, lens, emb, ws, out);
  } else {
    hipLaunchKernelGGL(init_kernel, dim3(1536), dim3(256), 0, stream, ws, out);
    for (int s = 0; s < TT; ++s) {
      hipLaunchKernelGGL(step_fused, dim3(8, 16, 2), dim3(256), 0, stream, tok,
                         lens, emb, wih_f, whh_f, b_f, wih_b, whh_b, b_b, ws,
                         out, s);
    }
  }
}